// Round 4
// baseline (537.508 us; speedup 1.0000x reference)
//
#include <hip/hip_runtime.h>
#include <stdint.h>

typedef __attribute__((ext_vector_type(8))) short bf16x8;
typedef __attribute__((ext_vector_type(4))) float f32x4;
typedef unsigned short ushort_t;
typedef unsigned int u32;
typedef const __attribute__((address_space(1))) u32* gp1_t;
typedef __attribute__((address_space(3))) u32* lp3_t;

#define MFMA(a,b,c) __builtin_amdgcn_mfma_f32_16x16x32_bf16((a),(b),(c),0,0,0)

static constexpr int BATCH = 64, LQ = 528, DIM = 768, NH = 12, DH = 64;
static constexpr int MTOK = BATCH * LQ;   // 33792
static constexpr int VTP  = 544;          // padded Vt row stride (keys)
// scale * log2(e): folded into Q so softmax is a bare exp2
static constexpr float QSCALE = (float)(0.03608439182435161 * 1.4426950408889634);

__device__ __forceinline__ ushort_t f2bf(float f) {
  u32 u = __float_as_uint(f);
  u = (u + 0x7fffu + ((u >> 16) & 1u)) >> 16;
  return (ushort_t)u;
}
__device__ __forceinline__ u32 pack2(u32 xr, u32 yr) {  // lo=yr.bf16, hi=xr.bf16
  return __builtin_amdgcn_perm(xr, yr, 0x07060302u);
}
__device__ __forceinline__ int swzK(int r) { return (r & 3) | (((r >> 3) & 1) << 2); }
__device__ __forceinline__ int swzV(int d) { return (d >> 2) & 3; }

// ---------------- conversion kernels ----------------
__global__ __launch_bounds__(256) void k_convert_x(const float* __restrict__ x,
                                                   ushort_t* __restrict__ xb) {
  int i = blockIdx.x * 256 + threadIdx.x;
  float4 v = ((const float4*)x)[i];
  ushort4 o;
  o.x = f2bf(v.x); o.y = f2bf(v.y); o.z = f2bf(v.z); o.w = f2bf(v.w);
  ((ushort4*)xb)[i] = o;
}

// LDS-tiled transpose: W[k][n] f32 -> Wt[n][k] bf16, coalesced both sides
__global__ __launch_bounds__(256) void k_convert_w(
    const float* __restrict__ w0, const float* __restrict__ w1,
    const float* __restrict__ w2, const float* __restrict__ w3,
    ushort_t* __restrict__ o0, ushort_t* __restrict__ o1,
    ushort_t* __restrict__ o2, ushort_t* __restrict__ o3) {
  __shared__ ushort_t t[64][65];
  int mid = blockIdx.z;
  const float* src = (mid == 0) ? w0 : (mid == 1) ? w1 : (mid == 2) ? w2 : w3;
  ushort_t* dst = (mid == 0) ? o0 : (mid == 1) ? o1 : (mid == 2) ? o2 : o3;
  int k0 = blockIdx.x * 64, n0 = blockIdx.y * 64;
  int c = threadIdx.x & 63, rr = threadIdx.x >> 6;
#pragma unroll
  for (int p = 0; p < 16; p++) {
    int r = p * 4 + rr;
    t[c][r] = f2bf(src[(size_t)(k0 + r) * DIM + n0 + c]);
  }
  __syncthreads();
#pragma unroll
  for (int p = 0; p < 16; p++) {
    int r = p * 4 + rr;
    dst[(size_t)(n0 + r) * DIM + k0 + c] = t[r][c];
  }
}

// ---------------- fused QKV GEMM v4: 256x256, 4-phase/K-tile, counted vmcnt --
// Staging unit = K-HALF (A or B, 32 cols, 16KB = 2 gload_lds/thread).
// Per-tile phases: P1{vmcnt(4),bar, ds h0 A0-3+B0-3, stage t+1.Ah0, 16 MFMA}
//                  P2{bar, ds h0 A4-7, stage t+1.Bh0, 16 MFMA}
//                  P3{vmcnt(4),bar, ds h1 A0-3+B0-3, stage t+1.Ah1, 16 MFMA}
//                  P4{bar, ds h1 A4-7, stage t+1.Bh1, 16 MFMA}
// Per-wave ledger: tile entry = 8 outstanding [Ah0,Bh0,Ah1,Bh1]x2; vmcnt(4) at
// P1 retires exactly {Ah0,Bh0}, at P3 exactly {Ah1,Bh1}. Never vmcnt(0) in loop.
// WAR: stages write slot^1 whose readers all passed this tile's P1 barrier.
// LDS 128KB (1 blk/CU): pipeline replaces occupancy (r2/r3 lesson: either
// pin+count or keep blocks; drain-to-0 with 1-2 blocks loses both).
// Swizzle for 64B rows: chunk ^ ((row>>1)&3) -> each 128B bank cycle served by
// 8 lanes on 8 distinct 16B granules (conflict-free ds_read_b128).
__global__ __launch_bounds__(512, 2) void k_gemm_qkv(
    const ushort_t* __restrict__ A, const ushort_t* __restrict__ wq,
    const ushort_t* __restrict__ wk, const ushort_t* __restrict__ wv,
    ushort_t* __restrict__ Qb, ushort_t* __restrict__ Kb, ushort_t* __restrict__ Vtb) {
  // bijective XCD swizzle over 1188 = 132 mT * 9 nT blocks
  const int orig = blockIdx.x, xcd = orig & 7, within = orig >> 3;
  const int wgid = (xcd < 4 ? xcd * 149 : 4 * 149 + (xcd - 4) * 148) + within;
  const int mT = wgid / 9, nT9 = wgid % 9;
  const int w = nT9 / 3, nc0 = (nT9 % 3) * 256;
  const ushort_t* Bt = (w == 0) ? wq : (w == 1) ? wk : wv;

  // [slot][unit: 0=A-h0 1=B-h0 2=A-h1 3=B-h1][256 rows * 32 cols]
  __shared__ ushort_t smem[2][4][8192];
  const int tid = threadIdx.x;
  const int wid = tid >> 6, lane = tid & 63;
  const int lane15 = lane & 15, quad = lane >> 4;
  const int wm = wid >> 2, wn = wid & 3;      // 2M x 4N waves, each 128x64 out

  f32x4 acc[8][4];
#pragma unroll
  for (int i = 0; i < 8; i++)
#pragma unroll
    for (int j = 0; j < 4; j++) acc[i][j] = (f32x4)0.0f;

  // stage one K-half unit u (0=Ah0,1=Bh0,2=Ah1,3=Bh1) of tile kt into slot sl
  auto stageH = [&](int sl, int u, int kt) {
    const int kb = kt * 64 + ((u >> 1) << 5);
    const ushort_t* src = (u & 1) ? Bt : A;
    const int rb = (u & 1) ? nc0 : mT * 256;
#pragma unroll
    for (int j = 0; j < 2; j++) {
      int row = j * 128 + (tid >> 2);
      int c = tid & 3;
      size_t off = (size_t)(rb + row) * 768 + kb + ((c ^ ((row >> 1) & 3)) << 3);
      __builtin_amdgcn_global_load_lds((gp1_t)(src + off),
          (lp3_t)&smem[sl][u][(j * 128 + wid * 16) * 32], 16, 0, 0);
    }
  };
  auto rdA = [&](int sl, int h, int mi) {
    int row = wm * 128 + mi * 16 + lane15;
    return *(const bf16x8*)&smem[sl][h * 2][row * 32 + ((quad ^ ((row >> 1) & 3)) << 3)];
  };
  auto rdB = [&](int sl, int h, int ni) {
    int row = wn * 64 + ni * 16 + lane15;
    return *(const bf16x8*)&smem[sl][h * 2 + 1][row * 32 + ((quad ^ ((row >> 1) & 3)) << 3)];
  };

#define VMCNT4 asm volatile("s_waitcnt vmcnt(4)" ::: "memory")
#define VMCNT0 asm volatile("s_waitcnt vmcnt(0)" ::: "memory")
#define SBAR   __builtin_amdgcn_s_barrier()
#define SCHED0 __builtin_amdgcn_sched_barrier(0)
#define PRIO1  __builtin_amdgcn_s_setprio(1)
#define PRIO0  __builtin_amdgcn_s_setprio(0)

  // prologue: issue tile 0's four units in ledger order
  stageH(0, 0, 0); stageH(0, 1, 0); stageH(0, 2, 0); stageH(0, 3, 0);

  for (int t = 0; t < 11; t++) {
    const int sl = t & 1, so = sl ^ 1;
    bf16x8 af[4], bf[4];
    // ---- P1: needs t.Ah0 + t.Bh0 (oldest 4 of 8 in flight)
    VMCNT4; SBAR; SCHED0;
#pragma unroll
    for (int i = 0; i < 4; i++) af[i] = rdA(sl, 0, i);
#pragma unroll
    for (int i = 0; i < 4; i++) bf[i] = rdB(sl, 0, i);
    stageH(so, 0, t + 1);
    SCHED0; PRIO1;
#pragma unroll
    for (int mi = 0; mi < 4; mi++)
#pragma unroll
      for (int ni = 0; ni < 4; ni++)
        acc[mi][ni] = MFMA(af[mi], bf[ni], acc[mi][ni]);
    PRIO0; SCHED0;
    // ---- P2: same h0 B frags, A rows 4-7
    SBAR; SCHED0;
#pragma unroll
    for (int i = 0; i < 4; i++) af[i] = rdA(sl, 0, 4 + i);
    stageH(so, 1, t + 1);
    SCHED0; PRIO1;
#pragma unroll
    for (int mi = 0; mi < 4; mi++)
#pragma unroll
      for (int ni = 0; ni < 4; ni++)
        acc[4 + mi][ni] = MFMA(af[mi], bf[ni], acc[4 + mi][ni]);
    PRIO0; SCHED0;
    // ---- P3: needs t.Ah1 + t.Bh1 (oldest 4 of current 8)
    VMCNT4; SBAR; SCHED0;
#pragma unroll
    for (int i = 0; i < 4; i++) af[i] = rdA(sl, 1, i);
#pragma unroll
    for (int i = 0; i < 4; i++) bf[i] = rdB(sl, 1, i);
    stageH(so, 2, t + 1);
    SCHED0; PRIO1;
#pragma unroll
    for (int mi = 0; mi < 4; mi++)
#pragma unroll
      for (int ni = 0; ni < 4; ni++)
        acc[mi][ni] = MFMA(af[mi], bf[ni], acc[mi][ni]);
    PRIO0; SCHED0;
    // ---- P4
    SBAR; SCHED0;
#pragma unroll
    for (int i = 0; i < 4; i++) af[i] = rdA(sl, 1, 4 + i);
    stageH(so, 3, t + 1);
    SCHED0; PRIO1;
#pragma unroll
    for (int mi = 0; mi < 4; mi++)
#pragma unroll
      for (int ni = 0; ni < 4; ni++)
        acc[4 + mi][ni] = MFMA(af[mi], bf[ni], acc[4 + mi][ni]);
    PRIO0; SCHED0;
  }
  // ---- peeled tail tile t=11 (slot 1): nothing left to stage
  {
    bf16x8 af[4], bf[4];
    VMCNT4; SBAR; SCHED0;   // Ah0+Bh0 of tile 11
#pragma unroll
    for (int i = 0; i < 4; i++) af[i] = rdA(1, 0, i);
#pragma unroll
    for (int i = 0; i < 4; i++) bf[i] = rdB(1, 0, i);
    PRIO1;
#pragma unroll
    for (int mi = 0; mi < 4; mi++)
#pragma unroll
      for (int ni = 0; ni < 4; ni++)
        acc[mi][ni] = MFMA(af[mi], bf[ni], acc[mi][ni]);
    PRIO0; SCHED0;
#pragma unroll
    for (int i = 0; i < 4; i++) af[i] = rdA(1, 0, 4 + i);
    PRIO1;
#pragma unroll
    for (int mi = 0; mi < 4; mi++)
#pragma unroll
      for (int ni = 0; ni < 4; ni++)
        acc[4 + mi][ni] = MFMA(af[mi], bf[ni], acc[4 + mi][ni]);
    PRIO0; SCHED0;
    VMCNT0; SBAR; SCHED0;   // Ah1+Bh1 of tile 11 (last in flight)
#pragma unroll
    for (int i = 0; i < 4; i++) af[i] = rdA(1, 1, i);
#pragma unroll
    for (int i = 0; i < 4; i++) bf[i] = rdB(1, 1, i);
    PRIO1;
#pragma unroll
    for (int mi = 0; mi < 4; mi++)
#pragma unroll
      for (int ni = 0; ni < 4; ni++)
        acc[mi][ni] = MFMA(af[mi], bf[ni], acc[mi][ni]);
    PRIO0; SCHED0;
#pragma unroll
    for (int i = 0; i < 4; i++) af[i] = rdA(1, 1, 4 + i);
    PRIO1;
#pragma unroll
    for (int mi = 0; mi < 4; mi++)
#pragma unroll
      for (int ni = 0; ni < 4; ni++)
        acc[4 + mi][ni] = MFMA(af[mi], bf[ni], acc[4 + mi][ni]);
    PRIO0; SCHED0;
  }
#undef VMCNT4
#undef VMCNT0
#undef SBAR
#undef SCHED0
#undef PRIO1
#undef PRIO0

  const float scalev = (w == 0) ? QSCALE : 1.0f;
  ushort_t* Cqk = (w == 0) ? Qb : Kb;
#pragma unroll
  for (int mi = 0; mi < 8; mi++) {
#pragma unroll
    for (int rr = 0; rr < 4; rr++) {
      int m = mT * 256 + wm * 128 + mi * 16 + quad * 4 + rr;
      int b = m / 528, lt = m - b * 528;
#pragma unroll
      for (int ni = 0; ni < 4; ni++) {
        int n = nc0 + wn * 64 + ni * 16 + lane15;
        float v = acc[mi][ni][rr];
        if (w < 2) {
          Cqk[(((size_t)(b * 12 + (n >> 6)) * 528 + lt) << 6) + (n & 63)] = f2bf(v * scalev);
        } else {
          Vtb[((size_t)(b * 12 + (n >> 6)) * 64 + (n & 63)) * VTP + lt] = f2bf(v);
        }
      }
    }
  }
}

// ---------------- out-proj GEMM v3: dbuf 2-phase structure (round-3 state) ---
__global__ __launch_bounds__(256, 2) void k_gemm_out(const ushort_t* __restrict__ A,
                                                     const ushort_t* __restrict__ Bt,
                                                     float* __restrict__ C,
                                                     const float* __restrict__ bias) {
  const int id = blockIdx.x, xcd = id & 7, s = id >> 3;  // 1584 = 8*(33*6)
  const int mT = xcd * 33 + s / 6, nT = s % 6;

  __shared__ ushort_t at[2][128 * 64];
  __shared__ ushort_t bt[2][128 * 64];
  const int tid = threadIdx.x;
  const int wv_ = tid >> 6, lane = tid & 63;
  const int lane15 = lane & 15, quad = lane >> 4;
  const int mw = (wv_ & 1) * 64, nw = (wv_ >> 1) * 64;

  f32x4 acc[4][4];
#pragma unroll
  for (int i = 0; i < 4; i++)
#pragma unroll
    for (int j = 0; j < 4; j++) acc[i][j] = (f32x4)0.0f;

  const int lrow = lane >> 3;
  const int lchunk = lane & 7;

  auto stage = [&](int p, int kb) {
#pragma unroll
    for (int i = 0; i < 4; i++) {
      int r0 = wv_ * 32 + i * 8;
      int lr = r0 + lrow;
      int grow = mT * 128 + lr;
      int gk = kb + ((lchunk ^ (lr & 7)) << 3);
      int b = grow / 528, ltk = grow - b * 528;
      size_t off = (((size_t)(b * 12 + (gk >> 6)) * 528 + ltk) << 6) + (gk & 63);
      __builtin_amdgcn_global_load_lds((gp1_t)(A + off), (lp3_t)(&at[p][r0 * 64]), 16, 0, 0);
    }
#pragma unroll
    for (int i = 0; i < 4; i++) {
      int r0 = wv_ * 32 + i * 8;
      int lr = r0 + lrow;
      size_t off = (size_t)(nT * 128 + lr) * 768 + kb + ((lchunk ^ (lr & 7)) << 3);
      __builtin_amdgcn_global_load_lds((gp1_t)(Bt + off), (lp3_t)(&bt[p][r0 * 64]), 16, 0, 0);
    }
  };

  stage(0, 0);
  __syncthreads();

  for (int kt = 0; kt < 12; kt++) {
    const int p = kt & 1;
    if (kt < 11) stage(p ^ 1, (kt + 1) * 64);
    __builtin_amdgcn_sched_barrier(0);
#pragma unroll
    for (int h = 0; h < 2; h++) {
      bf16x8 af[4], bf[4];
#pragma unroll
      for (int mi = 0; mi < 4; mi++) {
        int row = mw + mi * 16 + lane15;
        af[mi] = *(const bf16x8*)&at[p][row * 64 + (((h * 4 + quad) ^ (row & 7)) << 3)];
      }
#pragma unroll
      for (int ni = 0; ni < 4; ni++) {
        int row = nw + ni * 16 + lane15;
        bf[ni] = *(const bf16x8*)&bt[p][row * 64 + (((h * 4 + quad) ^ (row & 7)) << 3)];
      }
#pragma unroll
      for (int mi = 0; mi < 4; mi++)
#pragma unroll
        for (int ni = 0; ni < 4; ni++)
          acc[mi][ni] = MFMA(af[mi], bf[ni], acc[mi][ni]);
    }
    __syncthreads();
  }

#pragma unroll
  for (int mi = 0; mi < 4; mi++) {
#pragma unroll
    for (int r = 0; r < 4; r++) {
      int m = mT * 128 + mw + mi * 16 + quad * 4 + r;
#pragma unroll
      for (int ni = 0; ni < 4; ni++) {
        int n = nT * 128 + nw + ni * 16 + lane15;
        C[(size_t)m * 768 + n] = acc[mi][ni][r] + bias[n];
      }
    }
  }
}

// ---------------- attention v4: block-coop LDS K/V pipeline ----------------
__global__ __launch_bounds__(256, 3) void k_attn(ushort_t* __restrict__ Q,
                                                 const ushort_t* __restrict__ K,
                                                 const ushort_t* __restrict__ Vt) {
  __shared__ ushort_t Ksh[2][32 * 64];
  __shared__ ushort_t Vsh[2][64 * 32];
  const int tid = threadIdx.x;
  const int wv = tid >> 6, lane = tid & 63;
  const int lane15 = lane & 15, quad = lane >> 4;
  const int b = blockIdx.x, xcd = b & 7, slot = b >> 3;
  const int g = slot / 17, r = slot - g * 17;
  const int bh0 = (xcd * 24 + g) * 4;

  bf16x8 ones;
#pragma unroll
  for (int i = 0; i < 8; i++) ones[i] = (short)0x3F80;

  const int krp = ((lane15 >> 2) << 3) + (lane15 & 3);

  if (r < 16) {  // ---- FULL / LIGHT: block-coop, LDS-shared K/V ----
    const int sub = r & 3;
    const int bh = bh0 + (r >> 2);
    const bool light = (sub == 3);
    const int rows0 = light ? (wv * 32) : (128 + sub * 128 + wv * 32);
    const int nch = light ? 4 : 17;

    ushort_t* Qb = Q + (size_t)bh * LQ * DH;
    const ushort_t* Kbh = K + (size_t)bh * LQ * DH;
    const ushort_t* Vbh = Vt + (size_t)bh * DH * VTP;

    bf16x8 aq[2][2];
#pragma unroll
    for (int mt = 0; mt < 2; mt++)
#pragma unroll
      for (int h = 0; h < 2; h++)
        aq[mt][h] = *(const bf16x8*)&Qb[(size_t)(rows0 + mt * 16 + lane15) * DH + h * 32 + quad * 8];

    f32x4 o[2][4], sm[2];
#pragma unroll
    for (int mt = 0; mt < 2; mt++) {
      sm[mt] = (f32x4)0.0f;
#pragma unroll
      for (int dt = 0; dt < 4; dt++) o[mt][dt] = (f32x4)0.0f;
    }

    auto stageKV = [&](int buf, int kc) {
      {
        int rr = tid >> 3, u = tid & 7;
        const ushort_t* src = Kbh + (size_t)(kc + rr) * DH + ((u ^ swzK(rr)) << 3);
        __builtin_amdgcn_global_load_lds((gp1_t)src, (lp3_t)&Ksh[buf][(wv * 8) * 64], 16, 0, 0);
      }
      {
        int d = tid >> 2, cc = tid & 3;
        const ushort_t* src = Vbh + (size_t)d * VTP + kc + ((cc ^ swzV(d)) << 3);
        __builtin_amdgcn_global_load_lds((gp1_t)src, (lp3_t)&Vsh[buf][(wv * 16) * 32], 16, 0, 0);
      }
    };

    stageKV(0, 0);
    for (int c = 0; c < nch; c++) {
      __syncthreads();
      if (c + 1 < nch) stageKV((c + 1) & 1, (c + 1) * 32);
      const int buf = c & 1;
      bf16x8 kf[2][2], vf[4];
#pragma unroll
      for (int ss = 0; ss < 2; ss++) {
        int kr = krp + ss * 4;
#pragma unroll
        for (int h = 0; h < 2; h++)
          kf[ss][h] = *(const bf16x8*)&Ksh[buf][kr * 64 + (((h * 4 + quad) ^ swzK(kr)) << 3)];
      }
#pragma unroll
      for (int dt = 0; dt < 4; dt++) {
        int d = dt * 16 + lane15;
        vf[dt] = *(const bf16x8*)&Vsh[buf][d * 32 + ((quad ^ swzV(d)) << 3)];
      }
      const bool maskl = (c == 16) && (quad >= 2);
#pragma unroll
      for (int mt = 0; mt < 2; mt++) {
        f32x4 c0 = (f32x4)0.0f, c1 = (f32x4)0.0f;
        c0 = MFMA(kf[0][0], aq[mt][0], c0);
        c0 = MFMA(kf[0][1], aq[mt][1], c0);
        c1 = MFMA(kf[1][0], aq[mt][0], c1);
        c1 = MFMA(kf[1][1], aq[mt][1], c1);
        u32 pw[8];
#pragma unroll
        for (int rr = 0; rr < 4; rr++) {
          float a0 = maskl ? -30.0f : c0[rr];
          float a1 = maskl ? -30.0f : c1[rr];
          pw[rr]     = __float_as_uint(exp2f(a0)) + 0x8000u;
          pw[4 + rr] = __float_as_uint(exp2f(a1)) + 0x8000u;
        }
        union { bf16x8 v; u32 w[4]; } pb;
        pb.w[0] = pack2(pw[1], pw[0]);
        pb.w[1] = pack2(pw[3], pw[2]);
        pb.w[2] = pack2(pw[5], pw[4]);
        pb.w[3] = pack2(pw[7], pw[6]);
        sm[mt] = MFMA(ones, pb.v, sm[mt]);
#pragma unroll
        for (int dt = 0; dt < 4; dt++)
          o[mt][dt] = MFMA(vf[dt], pb.v, o[mt][dt]);
      }
    }

#pragma unroll
    for (int mt = 0; mt < 2; mt++) {
      float inv = 1.0f / sm[mt][0];
      ushort_t* orow = &Qb[(size_t)(rows0 + mt * 16 + lane15) * DH];
#pragma unroll
      for (int dt = 0; dt < 4; dt++) {
        u32 r0 = __float_as_uint(o[mt][dt][0] * inv) + 0x8000u;
        u32 r1 = __float_as_uint(o[mt][dt][1] * inv) + 0x8000u;
        u32 r2 = __float_as_uint(o[mt][dt][2] * inv) + 0x8000u;
        u32 r3 = __float_as_uint(o[mt][dt][3] * inv) + 0x8000u;
        uint2 st;
        st.x = pack2(r1, r0);
        st.y = pack2(r3, r2);
        *(uint2*)&orow[dt * 16 + quad * 4] = st;
      }
    }
  } else {  // ---- TAIL: 4 waves, each bh0+wv rows 512-527, register path ----
    const int bh = bh0 + wv;
    ushort_t* Qb = Q + (size_t)bh * LQ * DH;
    const ushort_t* Kbh = K + (size_t)bh * LQ * DH;
    const ushort_t* Vbh = Vt + (size_t)bh * DH * VTP;

    bf16x8 aq[2];
#pragma unroll
    for (int h = 0; h < 2; h++)
      aq[h] = *(const bf16x8*)&Qb[(size_t)(512 + lane15) * DH + h * 32 + quad * 8];

    f32x4 o[4], sm = (f32x4)0.0f;
#pragma unroll
    for (int dt = 0; dt < 4; dt++) o[dt] = (f32x4)0.0f;

    const ushort_t* kbase = Kbh + (size_t)krp * DH + quad * 8;
    const ushort_t* vbase = Vbh + (size_t)lane15 * VTP + quad * 8;

    for (int kc = 0; kc < 528; kc += 32) {
      bf16x8 kf[2][2], vf[4];
#pragma unroll
      for (int ss = 0; ss < 2; ss++) {
        const ushort_t* p = kbase + (size_t)(kc + ss * 4) * DH;
        kf[ss][0] = *(const bf16x8*)&p[0];
        kf[ss][1] = *(const bf16x8*)&p[32];
      }
#pragma unroll
      for (int dt = 0; dt < 4; dt++)
        vf[dt] = *(const bf16x8*)&vbase[(size_t)dt * 16 * VTP + kc];

      f32x4 c0 = (f32x4)0.0f, c1 = (f32x4)0.0f;
      c0 = MFMA(kf[0][0], aq[0], c0);
      c0 = MFMA(kf[0][1], aq[1], c0);
      c1 = MFMA(kf[1][0], aq[0], c1);
      c1 = MFMA(kf[1][1], aq[1], c1);
      const bool maskl = (kc == 512) && (quad >= 2);
      u32 pw[8];
#pragma unroll
      for (int rr = 0; rr < 4; rr++) {
        float a0 = maskl ? -30.0f : c0[rr];
        float a1 = maskl ? -30.0f : c1[rr];
        pw[rr]     = __float_as_uint(exp2f(a0)) + 0x8000u;
        pw[4 + rr] = __float_as_uint(exp2f(a1)) + 0x8000u;
      }
      union { bf16x8 v; u32 w[4]; } pb;
      pb.w[0] = pack2(pw[1], pw[0]);
      pb.w[1] = pack2(pw[3], pw[2]);
      pb.w[2] = pack2(pw[5], pw[4]);
      pb.w[3] = pack2(pw[7], pw[6]);
      sm = MFMA(ones, pb.v, sm);
#pragma unroll
      for (int dt = 0; dt < 4; dt++)
        o[dt] = MFMA(vf[dt], pb.v, o[dt]);
    }

    float inv = 1.0f / sm[0];
    ushort_t* orow = &Qb[(size_t)(512 + lane15) * DH];
#pragma unroll
    for (int dt = 0; dt < 4; dt++) {
      u32 r0 = __float_as_uint(o[dt][0] * inv) + 0x8000u;
      u32 r1 = __float_as_uint(o[dt][1] * inv) + 0x8000u;
      u32 r2 = __float_as_uint(o[dt][2] * inv) + 0x8000u;
      u32 r3 = __float_as_uint(o[dt][3] * inv) + 0x8000u;
      uint2 st;
      st.x = pack2(r1, r0);
      st.y = pack2(r3, r2);
      *(uint2*)&orow[dt * 16 + quad * 4] = st;
    }
  }
}

// ---------------- launch ----------------
extern "C" void kernel_launch(void* const* d_in, const int* in_sizes, int n_in,
                              void* d_out, int out_size, void* d_ws, size_t ws_size,
                              hipStream_t stream) {
  const float* x = (const float*)d_in[0];
  const float* Wq = (const float*)d_in[1];
  const float* Wk = (const float*)d_in[2];
  const float* Wv = (const float*)d_in[3];
  const float* Wp = (const float*)d_in[4];
  const float* bp = (const float*)d_in[5];
  float* out = (float*)d_out;

  char* ws = (char*)d_ws;
  size_t off = 0;
  auto alloc = [&](size_t bytes) {
    void* p = ws + off;
    off += (bytes + 255) & ~(size_t)255;
    return p;
  };
  ushort_t* xb = (ushort_t*)alloc((size_t)MTOK * DIM * 2);
  ushort_t* wtq = (ushort_t*)alloc((size_t)DIM * DIM * 2);
  ushort_t* wtk = (ushort_t*)alloc((size_t)DIM * DIM * 2);
  ushort_t* wtv = (ushort_t*)alloc((size_t)DIM * DIM * 2);
  ushort_t* wtp = (ushort_t*)alloc((size_t)DIM * DIM * 2);
  ushort_t* Qb = (ushort_t*)alloc((size_t)MTOK * DIM * 2);   // Q, then attn out in-place
  ushort_t* Kb = (ushort_t*)alloc((size_t)MTOK * DIM * 2);
  ushort_t* Vtb = (ushort_t*)alloc((size_t)BATCH * NH * DH * VTP * 2);
  (void)ws_size; (void)in_sizes; (void)n_in; (void)out_size;

  k_convert_x<<<25344, 256, 0, stream>>>(x, xb);
  k_convert_w<<<dim3(12, 12, 4), 256, 0, stream>>>(Wq, Wk, Wv, Wp, wtq, wtk, wtv, wtp);
  k_gemm_qkv<<<1188, 512, 0, stream>>>(xb, wtq, wtk, wtv, Qb, Kb, Vtb);
  k_attn<<<3264, 256, 0, stream>>>(Qb, Kb, Vtb);
  k_gemm_out<<<1584, 256, 0, stream>>>(Qb, wtp, out, bp);
}

// Round 5
// 473.027 us; speedup vs baseline: 1.1363x; 1.1363x over previous
//
#include <hip/hip_runtime.h>
#include <stdint.h>

typedef __attribute__((ext_vector_type(8))) short bf16x8;
typedef __attribute__((ext_vector_type(4))) float f32x4;
typedef unsigned short ushort_t;
typedef unsigned int u32;
typedef const __attribute__((address_space(1))) u32* gp1_t;
typedef __attribute__((address_space(3))) u32* lp3_t;

#define MFMA(a,b,c) __builtin_amdgcn_mfma_f32_16x16x32_bf16((a),(b),(c),0,0,0)

static constexpr int BATCH = 64, LQ = 528, DIM = 768, NH = 12, DH = 64;
static constexpr int MTOK = BATCH * LQ;   // 33792
static constexpr int VTP  = 544;          // padded Vt row stride (keys)
// scale * log2(e): folded into Q so softmax is a bare exp2
static constexpr float QSCALE = (float)(0.03608439182435161 * 1.4426950408889634);

__device__ __forceinline__ ushort_t f2bf(float f) {
  u32 u = __float_as_uint(f);
  u = (u + 0x7fffu + ((u >> 16) & 1u)) >> 16;
  return (ushort_t)u;
}
__device__ __forceinline__ u32 pack2(u32 xr, u32 yr) {  // lo=yr.bf16, hi=xr.bf16
  return __builtin_amdgcn_perm(xr, yr, 0x07060302u);
}
// packed 2xf32 -> 2xbf16 (RNE) in ONE VALU op: lo=bf16(a), hi=bf16(b)
__device__ __forceinline__ u32 cvtpk(float a, float b) {
  u32 r;
  asm("v_cvt_pk_bf16_f32 %0, %1, %2" : "=v"(r) : "v"(a), "v"(b));
  return r;
}
__device__ __forceinline__ int swzK(int r) { return (r & 3) | (((r >> 3) & 1) << 2); }
__device__ __forceinline__ int swzV(int d) { return (d >> 2) & 3; }

// ---------------- conversion kernels ----------------
__global__ __launch_bounds__(256) void k_convert_x(const float* __restrict__ x,
                                                   ushort_t* __restrict__ xb) {
  int i = blockIdx.x * 256 + threadIdx.x;
  float4 v = ((const float4*)x)[i];
  ushort4 o;
  o.x = f2bf(v.x); o.y = f2bf(v.y); o.z = f2bf(v.z); o.w = f2bf(v.w);
  ((ushort4*)xb)[i] = o;
}

// LDS-tiled transpose: W[k][n] f32 -> Wt[n][k] bf16, coalesced both sides
__global__ __launch_bounds__(256) void k_convert_w(
    const float* __restrict__ w0, const float* __restrict__ w1,
    const float* __restrict__ w2, const float* __restrict__ w3,
    ushort_t* __restrict__ o0, ushort_t* __restrict__ o1,
    ushort_t* __restrict__ o2, ushort_t* __restrict__ o3) {
  __shared__ ushort_t t[64][65];
  int mid = blockIdx.z;
  const float* src = (mid == 0) ? w0 : (mid == 1) ? w1 : (mid == 2) ? w2 : w3;
  ushort_t* dst = (mid == 0) ? o0 : (mid == 1) ? o1 : (mid == 2) ? o2 : o3;
  int k0 = blockIdx.x * 64, n0 = blockIdx.y * 64;
  int c = threadIdx.x & 63, rr = threadIdx.x >> 6;
#pragma unroll
  for (int p = 0; p < 16; p++) {
    int r = p * 4 + rr;
    t[c][r] = f2bf(src[(size_t)(k0 + r) * DIM + n0 + c]);
  }
  __syncthreads();
#pragma unroll
  for (int p = 0; p < 16; p++) {
    int r = p * 4 + rr;
    dst[(size_t)(n0 + r) * DIM + k0 + c] = t[r][c];
  }
}

// ---------------- fused QKV GEMM (round-1 proven structure, 186us) ----------
// 128x128 tile, BK=64, single LDS buffer, XOR-swizzled, gload_lds w=16,
// 2 barriers/K-step, 32KB LDS -> ~3 blocks/CU implicit overlap.
// r2/r3/r4 lesson: every deeper-pipeline variant (dbuf vmcnt0 1blk, dbuf
// pinned 1.6blk, 4-phase counted-vmcnt 1blk) lost 15-40% at this short K=768.
__global__ __launch_bounds__(256, 2) void k_gemm_qkv(
    const ushort_t* __restrict__ A, const ushort_t* __restrict__ wq,
    const ushort_t* __restrict__ wk, const ushort_t* __restrict__ wv,
    ushort_t* __restrict__ Qb, ushort_t* __restrict__ Kb, ushort_t* __restrict__ Vtb) {
  // XCD swizzle: 4752 = 8 * (33 mT * 18 nt); same-mT blocks consecutive per XCD
  const int id = blockIdx.x, xcd = id & 7, s = id >> 3;
  const int mT = xcd * 33 + s / 18, t = s % 18, w = t / 6, nT = t % 6;
  const ushort_t* Bt = (w == 0) ? wq : (w == 1) ? wk : wv;

  __shared__ ushort_t at[128 * 64];
  __shared__ ushort_t bt[128 * 64];
  const int tid = threadIdx.x;
  const int wv_ = tid >> 6, lane = tid & 63;
  const int lane15 = lane & 15, quad = lane >> 4;
  const int mw = (wv_ & 1) * 64, nw = (wv_ >> 1) * 64;

  f32x4 acc[4][4];
#pragma unroll
  for (int i = 0; i < 4; i++)
#pragma unroll
    for (int j = 0; j < 4; j++) acc[i][j] = (f32x4)0.0f;

  const int lrow = lane >> 3;    // 0..7
  const int lchunk = lane & 7;   // 0..7

  for (int kb = 0; kb < 768; kb += 64) {
#pragma unroll
    for (int i = 0; i < 4; i++) {
      int r0 = wv_ * 32 + i * 8;
      int lr = r0 + lrow;
      size_t off = (size_t)(mT * 128 + lr) * 768 + kb + ((lchunk ^ (lr & 7)) << 3);
      __builtin_amdgcn_global_load_lds((gp1_t)(A + off), (lp3_t)(&at[r0 * 64]), 16, 0, 0);
    }
#pragma unroll
    for (int i = 0; i < 4; i++) {
      int r0 = wv_ * 32 + i * 8;
      int lr = r0 + lrow;
      size_t off = (size_t)(nT * 128 + lr) * 768 + kb + ((lchunk ^ (lr & 7)) << 3);
      __builtin_amdgcn_global_load_lds((gp1_t)(Bt + off), (lp3_t)(&bt[r0 * 64]), 16, 0, 0);
    }
    __syncthreads();
#pragma unroll
    for (int h = 0; h < 2; h++) {
      bf16x8 af[4], bf[4];
#pragma unroll
      for (int mi = 0; mi < 4; mi++) {
        int row = mw + mi * 16 + lane15;
        af[mi] = *(const bf16x8*)&at[row * 64 + (((h * 4 + quad) ^ (row & 7)) << 3)];
      }
#pragma unroll
      for (int ni = 0; ni < 4; ni++) {
        int row = nw + ni * 16 + lane15;
        bf[ni] = *(const bf16x8*)&bt[row * 64 + (((h * 4 + quad) ^ (row & 7)) << 3)];
      }
#pragma unroll
      for (int mi = 0; mi < 4; mi++)
#pragma unroll
        for (int ni = 0; ni < 4; ni++)
          acc[mi][ni] = MFMA(af[mi], bf[ni], acc[mi][ni]);
    }
    __syncthreads();
  }

  const float scale = (w == 0) ? QSCALE : 1.0f;
  ushort_t* Cqk = (w == 0) ? Qb : Kb;
#pragma unroll
  for (int mi = 0; mi < 4; mi++) {
#pragma unroll
    for (int r = 0; r < 4; r++) {
      int m = mT * 128 + mw + mi * 16 + quad * 4 + r;
      int b = m / 528, lt = m - b * 528;
#pragma unroll
      for (int ni = 0; ni < 4; ni++) {
        int n = nT * 128 + nw + ni * 16 + lane15;
        float v = acc[mi][ni][r];
        if (w < 2) {
          Cqk[(((size_t)(b * 12 + (n >> 6)) * 528 + lt) << 6) + (n & 63)] = f2bf(v * scale);
        } else {
          Vtb[((size_t)(b * 12 + (n >> 6)) * 64 + (n & 63)) * VTP + lt] = f2bf(v);
        }
      }
    }
  }
}

// ---------------- out-proj GEMM (round-1 proven structure) -------------------
__global__ __launch_bounds__(256, 2) void k_gemm_out(const ushort_t* __restrict__ A,
                                                     const ushort_t* __restrict__ Bt,
                                                     float* __restrict__ C,
                                                     const float* __restrict__ bias) {
  const int id = blockIdx.x, xcd = id & 7, s = id >> 3;  // 1584 = 8*(33*6)
  const int mT = xcd * 33 + s / 6, nT = s % 6;

  __shared__ ushort_t at[128 * 64];
  __shared__ ushort_t bt[128 * 64];
  const int tid = threadIdx.x;
  const int wv_ = tid >> 6, lane = tid & 63;
  const int lane15 = lane & 15, quad = lane >> 4;
  const int mw = (wv_ & 1) * 64, nw = (wv_ >> 1) * 64;

  f32x4 acc[4][4];
#pragma unroll
  for (int i = 0; i < 4; i++)
#pragma unroll
    for (int j = 0; j < 4; j++) acc[i][j] = (f32x4)0.0f;

  const int lrow = lane >> 3;
  const int lchunk = lane & 7;

  for (int kb = 0; kb < 768; kb += 64) {
#pragma unroll
    for (int i = 0; i < 4; i++) {
      int r0 = wv_ * 32 + i * 8;
      int lr = r0 + lrow;
      int grow = mT * 128 + lr;
      int gk = kb + ((lchunk ^ (lr & 7)) << 3);
      int b = grow / 528, ltk = grow - b * 528;
      size_t off = (((size_t)(b * 12 + (gk >> 6)) * 528 + ltk) << 6) + (gk & 63);
      __builtin_amdgcn_global_load_lds((gp1_t)(A + off), (lp3_t)(&at[r0 * 64]), 16, 0, 0);
    }
#pragma unroll
    for (int i = 0; i < 4; i++) {
      int r0 = wv_ * 32 + i * 8;
      int lr = r0 + lrow;
      size_t off = (size_t)(nT * 128 + lr) * 768 + kb + ((lchunk ^ (lr & 7)) << 3);
      __builtin_amdgcn_global_load_lds((gp1_t)(Bt + off), (lp3_t)(&bt[r0 * 64]), 16, 0, 0);
    }
    __syncthreads();
#pragma unroll
    for (int h = 0; h < 2; h++) {
      bf16x8 af[4], bf[4];
#pragma unroll
      for (int mi = 0; mi < 4; mi++) {
        int row = mw + mi * 16 + lane15;
        af[mi] = *(const bf16x8*)&at[row * 64 + (((h * 4 + quad) ^ (row & 7)) << 3)];
      }
#pragma unroll
      for (int ni = 0; ni < 4; ni++) {
        int row = nw + ni * 16 + lane15;
        bf[ni] = *(const bf16x8*)&bt[row * 64 + (((h * 4 + quad) ^ (row & 7)) << 3)];
      }
#pragma unroll
      for (int mi = 0; mi < 4; mi++)
#pragma unroll
        for (int ni = 0; ni < 4; ni++)
          acc[mi][ni] = MFMA(af[mi], bf[ni], acc[mi][ni]);
    }
    __syncthreads();
  }

#pragma unroll
  for (int mi = 0; mi < 4; mi++) {
#pragma unroll
    for (int r = 0; r < 4; r++) {
      int m = mT * 128 + mw + mi * 16 + quad * 4 + r;
#pragma unroll
      for (int ni = 0; ni < 4; ni++) {
        int n = nT * 128 + nw + ni * 16 + lane15;
        C[(size_t)m * 768 + n] = acc[mi][ni][r] + bias[n];
      }
    }
  }
}

// ---------------- attention v5: VALU-trimmed (cvt_pk pack + peeled mask) -----
// VALU-bound (per chunk-wave: ~18 MFMA vs ~200 VALU cyc). Cuts:
//  (1) v_cvt_pk_bf16_f32 replaces add+add+perm per bf16 pair (-24 ops/chunk)
//  (2) mask chunk (c==16) peeled: cndmask selects exist in 1/17 chunks only
__global__ __launch_bounds__(256, 3) void k_attn(ushort_t* __restrict__ Q,
                                                 const ushort_t* __restrict__ K,
                                                 const ushort_t* __restrict__ Vt) {
  __shared__ ushort_t Ksh[2][32 * 64];
  __shared__ ushort_t Vsh[2][64 * 32];
  const int tid = threadIdx.x;
  const int wv = tid >> 6, lane = tid & 63;
  const int lane15 = lane & 15, quad = lane >> 4;
  const int b = blockIdx.x, xcd = b & 7, slot = b >> 3;
  const int g = slot / 17, r = slot - g * 17;
  const int bh0 = (xcd * 24 + g) * 4;

  bf16x8 ones;
#pragma unroll
  for (int i = 0; i < 8; i++) ones[i] = (short)0x3F80;

  const int krp = ((lane15 >> 2) << 3) + (lane15 & 3);

  if (r < 16) {  // ---- FULL / LIGHT: block-coop, LDS-shared K/V ----
    const int sub = r & 3;
    const int bh = bh0 + (r >> 2);
    const bool light = (sub == 3);
    const int rows0 = light ? (wv * 32) : (128 + sub * 128 + wv * 32);
    const int nch = light ? 4 : 17;

    ushort_t* Qb = Q + (size_t)bh * LQ * DH;
    const ushort_t* Kbh = K + (size_t)bh * LQ * DH;
    const ushort_t* Vbh = Vt + (size_t)bh * DH * VTP;

    bf16x8 aq[2][2];
#pragma unroll
    for (int mt = 0; mt < 2; mt++)
#pragma unroll
      for (int h = 0; h < 2; h++)
        aq[mt][h] = *(const bf16x8*)&Qb[(size_t)(rows0 + mt * 16 + lane15) * DH + h * 32 + quad * 8];

    f32x4 o[2][4], sm[2];
#pragma unroll
    for (int mt = 0; mt < 2; mt++) {
      sm[mt] = (f32x4)0.0f;
#pragma unroll
      for (int dt = 0; dt < 4; dt++) o[mt][dt] = (f32x4)0.0f;
    }

    auto stageKV = [&](int buf, int kc) {
      {
        int rr = tid >> 3, u = tid & 7;
        const ushort_t* src = Kbh + (size_t)(kc + rr) * DH + ((u ^ swzK(rr)) << 3);
        __builtin_amdgcn_global_load_lds((gp1_t)src, (lp3_t)&Ksh[buf][(wv * 8) * 64], 16, 0, 0);
      }
      {
        int d = tid >> 2, cc = tid & 3;
        const ushort_t* src = Vbh + (size_t)d * VTP + kc + ((cc ^ swzV(d)) << 3);
        __builtin_amdgcn_global_load_lds((gp1_t)src, (lp3_t)&Vsh[buf][(wv * 16) * 32], 16, 0, 0);
      }
    };

    auto do_chunk = [&](int c, bool domask) {
      const int buf = c & 1;
      bf16x8 kf[2][2], vf[4];
#pragma unroll
      for (int ss = 0; ss < 2; ss++) {
        int kr = krp + ss * 4;
#pragma unroll
        for (int h = 0; h < 2; h++)
          kf[ss][h] = *(const bf16x8*)&Ksh[buf][kr * 64 + (((h * 4 + quad) ^ swzK(kr)) << 3)];
      }
#pragma unroll
      for (int dt = 0; dt < 4; dt++) {
        int d = dt * 16 + lane15;
        vf[dt] = *(const bf16x8*)&Vsh[buf][d * 32 + ((quad ^ swzV(d)) << 3)];
      }
      const bool maskl = domask && (quad >= 2);
#pragma unroll
      for (int mt = 0; mt < 2; mt++) {
        f32x4 c0 = (f32x4)0.0f, c1 = (f32x4)0.0f;
        c0 = MFMA(kf[0][0], aq[mt][0], c0);
        c0 = MFMA(kf[0][1], aq[mt][1], c0);
        c1 = MFMA(kf[1][0], aq[mt][0], c1);
        c1 = MFMA(kf[1][1], aq[mt][1], c1);
        float e[8];
#pragma unroll
        for (int rr = 0; rr < 4; rr++) {
          e[rr]     = exp2f(maskl ? -30.0f : c0[rr]);
          e[4 + rr] = exp2f(maskl ? -30.0f : c1[rr]);
        }
        union { bf16x8 v; u32 w[4]; } pb;
        pb.w[0] = cvtpk(e[0], e[1]);
        pb.w[1] = cvtpk(e[2], e[3]);
        pb.w[2] = cvtpk(e[4], e[5]);
        pb.w[3] = cvtpk(e[6], e[7]);
        sm[mt] = MFMA(ones, pb.v, sm[mt]);
#pragma unroll
        for (int dt = 0; dt < 4; dt++)
          o[mt][dt] = MFMA(vf[dt], pb.v, o[mt][dt]);
      }
    };

    stageKV(0, 0);
    for (int c = 0; c < nch; c++) {
      __syncthreads();
      if (c + 1 < nch) stageKV((c + 1) & 1, (c + 1) * 32);
      if (c == 16) do_chunk(c, true);   // only the last FULL chunk masks keys >=528
      else         do_chunk(c, false);  // hot path: no mask selects
    }

#pragma unroll
    for (int mt = 0; mt < 2; mt++) {
      float inv = 1.0f / sm[mt][0];
      ushort_t* orow = &Qb[(size_t)(rows0 + mt * 16 + lane15) * DH];
#pragma unroll
      for (int dt = 0; dt < 4; dt++) {
        uint2 st;
        st.x = cvtpk(o[mt][dt][0] * inv, o[mt][dt][1] * inv);
        st.y = cvtpk(o[mt][dt][2] * inv, o[mt][dt][3] * inv);
        *(uint2*)&orow[dt * 16 + quad * 4] = st;
      }
    }
  } else {  // ---- TAIL: 4 waves, each bh0+wv rows 512-527, register path ----
    const int bh = bh0 + wv;
    ushort_t* Qb = Q + (size_t)bh * LQ * DH;
    const ushort_t* Kbh = K + (size_t)bh * LQ * DH;
    const ushort_t* Vbh = Vt + (size_t)bh * DH * VTP;

    bf16x8 aq[2];
#pragma unroll
    for (int h = 0; h < 2; h++)
      aq[h] = *(const bf16x8*)&Qb[(size_t)(512 + lane15) * DH + h * 32 + quad * 8];

    f32x4 o[4], sm = (f32x4)0.0f;
#pragma unroll
    for (int dt = 0; dt < 4; dt++) o[dt] = (f32x4)0.0f;

    const ushort_t* kbase = Kbh + (size_t)krp * DH + quad * 8;
    const ushort_t* vbase = Vbh + (size_t)lane15 * VTP + quad * 8;

    for (int kc = 0; kc < 528; kc += 32) {
      bf16x8 kf[2][2], vf[4];
#pragma unroll
      for (int ss = 0; ss < 2; ss++) {
        const ushort_t* p = kbase + (size_t)(kc + ss * 4) * DH;
        kf[ss][0] = *(const bf16x8*)&p[0];
        kf[ss][1] = *(const bf16x8*)&p[32];
      }
#pragma unroll
      for (int dt = 0; dt < 4; dt++)
        vf[dt] = *(const bf16x8*)&vbase[(size_t)dt * 16 * VTP + kc];

      f32x4 c0 = (f32x4)0.0f, c1 = (f32x4)0.0f;
      c0 = MFMA(kf[0][0], aq[0], c0);
      c0 = MFMA(kf[0][1], aq[1], c0);
      c1 = MFMA(kf[1][0], aq[0], c1);
      c1 = MFMA(kf[1][1], aq[1], c1);
      const bool maskl = (kc == 512) && (quad >= 2);
      float e[8];
#pragma unroll
      for (int rr = 0; rr < 4; rr++) {
        e[rr]     = exp2f(maskl ? -30.0f : c0[rr]);
        e[4 + rr] = exp2f(maskl ? -30.0f : c1[rr]);
      }
      union { bf16x8 v; u32 w[4]; } pb;
      pb.w[0] = cvtpk(e[0], e[1]);
      pb.w[1] = cvtpk(e[2], e[3]);
      pb.w[2] = cvtpk(e[4], e[5]);
      pb.w[3] = cvtpk(e[6], e[7]);
      sm = MFMA(ones, pb.v, sm);
#pragma unroll
      for (int dt = 0; dt < 4; dt++)
        o[dt] = MFMA(vf[dt], pb.v, o[dt]);
    }

    float inv = 1.0f / sm[0];
    ushort_t* orow = &Qb[(size_t)(512 + lane15) * DH];
#pragma unroll
    for (int dt = 0; dt < 4; dt++) {
      uint2 st;
      st.x = cvtpk(o[dt][0] * inv, o[dt][1] * inv);
      st.y = cvtpk(o[dt][2] * inv, o[dt][3] * inv);
      *(uint2*)&orow[dt * 16 + quad * 4] = st;
    }
  }
}

// ---------------- launch ----------------
extern "C" void kernel_launch(void* const* d_in, const int* in_sizes, int n_in,
                              void* d_out, int out_size, void* d_ws, size_t ws_size,
                              hipStream_t stream) {
  const float* x = (const float*)d_in[0];
  const float* Wq = (const float*)d_in[1];
  const float* Wk = (const float*)d_in[2];
  const float* Wv = (const float*)d_in[3];
  const float* Wp = (const float*)d_in[4];
  const float* bp = (const float*)d_in[5];
  float* out = (float*)d_out;

  char* ws = (char*)d_ws;
  size_t off = 0;
  auto alloc = [&](size_t bytes) {
    void* p = ws + off;
    off += (bytes + 255) & ~(size_t)255;
    return p;
  };
  ushort_t* xb = (ushort_t*)alloc((size_t)MTOK * DIM * 2);
  ushort_t* wtq = (ushort_t*)alloc((size_t)DIM * DIM * 2);
  ushort_t* wtk = (ushort_t*)alloc((size_t)DIM * DIM * 2);
  ushort_t* wtv = (ushort_t*)alloc((size_t)DIM * DIM * 2);
  ushort_t* wtp = (ushort_t*)alloc((size_t)DIM * DIM * 2);
  ushort_t* Qb = (ushort_t*)alloc((size_t)MTOK * DIM * 2);   // Q, then attn out in-place
  ushort_t* Kb = (ushort_t*)alloc((size_t)MTOK * DIM * 2);
  ushort_t* Vtb = (ushort_t*)alloc((size_t)BATCH * NH * DH * VTP * 2);
  (void)ws_size; (void)in_sizes; (void)n_in; (void)out_size;

  k_convert_x<<<25344, 256, 0, stream>>>(x, xb);
  k_convert_w<<<dim3(12, 12, 4), 256, 0, stream>>>(Wq, Wk, Wv, Wp, wtq, wtk, wtv, wtp);
  k_gemm_qkv<<<4752, 256, 0, stream>>>(xb, wtq, wtk, wtv, Qb, Kb, Vtb);
  k_attn<<<3264, 256, 0, stream>>>(Qb, Kb, Vtb);
  k_gemm_out<<<1584, 256, 0, stream>>>(Qb, wtp, out, bp);
}